// Round 14
// baseline (206.143 us; speedup 1.0000x reference)
//
#include <hip/hip_runtime.h>
#include <stdint.h>

typedef unsigned int u32;
typedef unsigned long long u64;

#define BB 8
#define NN 8192
#define CC 80
#define KK 1000
#define NC (NN*CC)            // 655360
#define MAXIDX (NC-1)
#define NMS_THR 0.5f
#define SCORE_THR 0.05f
#define MAX_RATIO 4.135166556742356f
#define CLS_OFF 10000.0f
#define CAP 2048
#define NW 16                 // u64 words per mask row
#define HB 8                  // hist1 sub-blocks per batch (1024 thr each)
#define SGB 128               // stage blocks per batch
#define D4X 8                 // refine blocks per batch (1024 thr each)
#define NTILE 136             // lower-triangle 64x64 tiles
#define LBUF 1024             // stage per-block staging buffer (u64)
#define GBUFCAP 98304         // per-batch superset capacity (u64)

// ---- workspace layout (bytes) ----
#define WS_HIST1   0          // BB*HB*2048*4 = 524288 (private slices, plain stores)
#define WS_HIST2   524288     // BB*2048*4 = 65536 (atomic-accumulated; zeroed by hist1)
#define WS_CTRL    589824     // 32 u32: gcount(8), spare(8), gcount2(8), spare(8)
#define WS_GCOUNT  589824
#define WS_GCOUNT2 589888
#define WS_GBUF    589952     // 8*98304*8 = 6291456 -> 6881408
#define WS_GBUF2   6881408    // 8*2048*8 = 131072 -> 7012480
#define WS_MASK    7012480    // 8*16*1000*8 = 1024000 -> 8036480

__device__ __forceinline__ u32 mapf(float f) {
    u32 u = __float_as_uint(f);
    return (u & 0x80000000u) ? ~u : (u | 0x80000000u);
}
__device__ __forceinline__ float unmapf(u32 m) {
    u32 u = (m & 0x80000000u) ? (m ^ 0x80000000u) : ~m;
    return __uint_as_float(u);
}

// ---------------- D1: private 11-bit histograms + fold-in zeroing of control bufs -----
__global__ __launch_bounds__(1024) void hist1_pass(const float* __restrict__ scores,
                                                   u32* __restrict__ hist1,
                                                   u32* __restrict__ hist2,
                                                   u32* __restrict__ ctrl /* 32 u32 */) {
    __shared__ u32 lh[2048];
    int b = blockIdx.y, blk = blockIdx.x, t = threadIdx.x;
    for (int i = t; i < 2048; i += 1024) lh[i] = 0;
    // zero hist2 slice (each of the 64 blocks zeroes 256 u32) and ctrl (block 0,0)
    if (t < 256) hist2[(b * HB + blk) * 256 + t] = 0u;
    else if (t < 288 && b == 0 && blk == 0) ctrl[t - 256] = 0u;
    __syncthreads();
    const float4* sp = (const float4*)(scores + (size_t)b * NC);
    int nvec = NC / 4;
    for (int v = blk * 1024 + t; v < nvec; v += HB * 1024) {
        float4 s4 = sp[v];
        float ss[4] = {s4.x, s4.y, s4.z, s4.w};
        #pragma unroll
        for (int q = 0; q < 4; ++q) {
            float s = ss[q] > SCORE_THR ? ss[q] : -1.0f;
            atomicAdd(&lh[mapf(s) >> 21], 1u);
        }
    }
    __syncthreads();
    u32* ho = hist1 + ((size_t)b * HB + blk) * 2048;
    for (int i = t; i < 2048; i += 1024) ho[i] = lh[i];
}

// ---- fast digit selects: wave shfl suffix-scan, 2 barriers total ----
// 256-thread version, 8 bins/thread (descending). bc[0]=digit, bc[1]=rem.
__device__ __forceinline__ void sel8_fast(const u32 hv[8], u32 need,
                                          u32* wt, u32* wsuf, u32* bc) {
    int t = threadIdx.x, l = t & 63, w = t >> 6;   // 4 waves
    u32 s = 0;
    #pragma unroll
    for (int q = 0; q < 8; ++q) s += hv[q];
    u32 x = s;
    #pragma unroll
    for (int off = 1; off < 64; off <<= 1) {
        u32 y = __shfl_down(x, off);
        if (l + off < 64) x += y;
    }
    if (l == 0) wt[w] = x;
    __syncthreads();
    if (w == 0) {
        u32 v = (l < 4) ? wt[l] : 0u;
        #pragma unroll
        for (int off = 1; off < 4; off <<= 1) {
            u32 y = __shfl_down(v, off);
            if (l + off < 4) v += y;
        }
        if (l < 4) wsuf[l] = v;
    }
    __syncthreads();
    u32 sufAll = x + ((w < 3) ? wsuf[w + 1] : 0u);
    u32 cumAbove = sufAll - s;
    if (cumAbove < need && sufAll >= need) {
        u32 cum = cumAbove;
        int d = t * 8;
        #pragma unroll
        for (int q = 7; q >= 0; --q) {
            if (cum + hv[q] >= need) { d = t * 8 + q; break; }
            cum += hv[q];
        }
        bc[0] = (u32)d;
        bc[1] = need - cum;
    }
    __syncthreads();
}

// 1024-thread version, 2 bins/thread (descending). bc[0]=digit, bc[1]=rem.
__device__ __forceinline__ void sel2_fast(u32 hv0, u32 hv1, u32 need,
                                          u32* wt, u32* wsuf, u32* bc) {
    int t = threadIdx.x, l = t & 63, w = t >> 6;   // 16 waves
    u32 s = hv0 + hv1;
    u32 x = s;
    #pragma unroll
    for (int off = 1; off < 64; off <<= 1) {
        u32 y = __shfl_down(x, off);
        if (l + off < 64) x += y;
    }
    if (l == 0) wt[w] = x;
    __syncthreads();
    if (w == 0) {
        u32 v = (l < 16) ? wt[l] : 0u;
        #pragma unroll
        for (int off = 1; off < 16; off <<= 1) {
            u32 y = __shfl_down(v, off);
            if (l + off < 16) v += y;
        }
        if (l < 16) wsuf[l] = v;
    }
    __syncthreads();
    u32 sufAll = x + ((w < 15) ? wsuf[w + 1] : 0u);
    u32 cumAbove = sufAll - s;
    if (cumAbove < need && sufAll >= need) {
        if (cumAbove + hv1 >= need) { bc[0] = 2u * t + 1u; bc[1] = need - cumAbove; }
        else                        { bc[0] = 2u * t;      bc[1] = need - cumAbove - hv1; }
    }
    __syncthreads();
}

// ---------------- D2: stage d0-superset + build hist2 (bits 20..10 of d0-items) ------
__global__ __launch_bounds__(256) void stage_pass(
    const float* __restrict__ scores, const u32* __restrict__ hist1,
    u32* __restrict__ hist2, u64* __restrict__ gbuf, u32* __restrict__ gcount) {
    __shared__ u64 buf[LBUF];
    __shared__ u32 h2[2048];
    __shared__ u32 wt[4], wsuf[4];
    __shared__ u32 bc[2];
    __shared__ u32 lcnt, lbase;
    int b = blockIdx.y, bx = blockIdx.x, t = threadIdx.x;
    for (int i = t; i < 2048; i += 256) h2[i] = 0;
    if (t == 0) lcnt = 0;
    u32 hv[8];
    {
        const u32* h = hist1 + (size_t)b * HB * 2048;
        #pragma unroll
        for (int q = 0; q < 8; ++q) {
            u32 v = 0;
            #pragma unroll
            for (int sb = 0; sb < HB; ++sb) v += h[sb * 2048 + t * 8 + q];
            hv[q] = v;
        }
    }
    __syncthreads();
    sel8_fast(hv, (u32)KK, wt, wsuf, bc);
    u32 d0 = bc[0];
    const float4* sp = (const float4*)(scores + (size_t)b * NC);
    int nvec = NC / 4;
    for (int v = bx * 256 + t; v < nvec; v += SGB * 256) {
        float4 s4 = sp[v];
        float ss[4] = {s4.x, s4.y, s4.z, s4.w};
        #pragma unroll
        for (int q = 0; q < 4; ++q) {
            float s = ss[q] > SCORE_THR ? ss[q] : -1.0f;
            u32 m = mapf(s);
            u32 top = m >> 21;
            if (top >= d0) {
                u32 p = atomicAdd(&lcnt, 1u);
                if (p < LBUF) {
                    u32 idx = (u32)(v * 4 + q);
                    buf[p] = ((u64)m << 32) | (u64)(MAXIDX - idx);
                }
                if (top == d0) atomicAdd(&h2[(m >> 10) & 0x7FFu], 1u);
            }
        }
    }
    __syncthreads();
    for (int i = t; i < 2048; i += 256)
        if (h2[i]) atomicAdd(&hist2[b * 2048 + i], h2[i]);
    if (t == 0) {
        u32 c = lcnt; if (c > LBUF) c = LBUF;
        lcnt = c;
        lbase = atomicAdd(&gcount[b], c);
    }
    __syncthreads();
    u32 c = lcnt, base = lbase;
    for (u32 i = t; i < c; i += 256) {
        u32 p = base + i;
        if (p < GBUFCAP) gbuf[(size_t)b * GBUFCAP + p] = buf[i];
    }
}

// ---------------- D3: exact 22-bit filter of staged superset -> gbuf2 ----------------
__global__ __launch_bounds__(1024) void refine_pass(
    const u64* __restrict__ gbuf, const u32* __restrict__ gcount,
    const u32* __restrict__ hist1, const u32* __restrict__ hist2,
    u64* __restrict__ gbuf2, u32* __restrict__ gcount2) {
    __shared__ u64 keys[CAP];
    __shared__ u32 wt[16], wsuf[16];
    __shared__ u32 bc[2];
    __shared__ u32 lcnt, lbase;
    int b = blockIdx.y, bx = blockIdx.x, t = threadIdx.x;
    if (t == 0) lcnt = 0;
    u32 hv0 = 0, hv1 = 0;
    {
        const u32* h = hist1 + (size_t)b * HB * 2048;
        #pragma unroll
        for (int sb = 0; sb < HB; ++sb) {
            hv0 += h[sb * 2048 + 2 * t];
            hv1 += h[sb * 2048 + 2 * t + 1];
        }
    }
    __syncthreads();
    sel2_fast(hv0, hv1, (u32)KK, wt, wsuf, bc);
    u32 d0 = bc[0], rem = bc[1];
    __syncthreads();
    sel2_fast(hist2[b * 2048 + 2 * t], hist2[b * 2048 + 2 * t + 1], rem, wt, wsuf, bc);
    u32 thr = ((d0 << 11) | bc[0]) << 10;

    u32 cnt = gcount[b]; if (cnt > GBUFCAP) cnt = GBUFCAP;
    const u64* gb = gbuf + (size_t)b * GBUFCAP;
    u32 chunk = (cnt + D4X - 1) / D4X;
    u32 lo = bx * chunk, hi = lo + chunk; if (hi > cnt) hi = cnt;
    for (u32 i = lo + t; i < hi; i += 1024) {
        u64 key = gb[i];
        if ((u32)(key >> 32) >= thr) {
            u32 p = atomicAdd(&lcnt, 1u);
            if (p < CAP) keys[p] = key;
        }
    }
    __syncthreads();
    if (t == 0) {
        u32 c = lcnt; if (c > CAP) c = CAP;
        lcnt = c;
        lbase = atomicAdd(&gcount2[b], c);      // default atomicAdd = device scope
    }
    __syncthreads();
    u32 c = lcnt, base = lbase;
    for (u32 i = t; i < c; i += 1024) {
        u32 p = base + i;
        if (p < CAP) gbuf2[(size_t)b * CAP + p] = keys[i];   // plain stores
    }
}

// ---- bitonic helpers ----
__device__ __forceinline__ u64 shfl_xor64(u64 v, int j) {
    return (u64)__shfl_xor((unsigned long long)v, j, 64);
}
__device__ __forceinline__ u64 bstep(u64 v, int i, int j, int k) {
    u64 w = shfl_xor64(v, j);
    bool desc = ((i & k) == 0);
    bool upper = ((i & j) != 0);
    u64 mx = (v > w) ? v : w;
    u64 mn = (v > w) ? w : v;
    return (desc != upper) ? mx : mn;
}

// ---------------- D4: fused tail — sort + decode(LDS) + IoU + NMS + output ----------
__global__ __launch_bounds__(1024) void tail_pass(
    const u64* __restrict__ gbuf2, const u32* __restrict__ gcount2,
    const float* __restrict__ rois, const float* __restrict__ reg,
    u64* __restrict__ maskT, float* __restrict__ out) {
    __shared__ u64 keys[CAP];      // 16 KB
    __shared__ float tb[KK][4];    // 16 KB decoded boxes
    __shared__ float ob[KK][4];    // 16 KB class-offset boxes
    __shared__ float ts[KK];       // 4 KB
    __shared__ float tc[KK];       // 4 KB
    __shared__ u32 tv[KK];         // 4 KB
    __shared__ u64 skept[NW];
    int b = blockIdx.x, t = threadIdx.x;

    // ---- load + shfl-hybrid bitonic sort (desc) ----
    u32 cnt2 = gcount2[b]; if (cnt2 > CAP) cnt2 = CAP;
    for (int i = t; i < CAP; i += 1024)
        keys[i] = (i < (int)cnt2) ? gbuf2[(size_t)b * CAP + i] : 0ull;
    __syncthreads();
    {
        const int i0 = t, i1 = t + 1024;
        u64 v0 = keys[i0], v1 = keys[i1];
        for (int k = 2; k <= 64; k <<= 1)
            for (int j = k >> 1; j >= 1; j >>= 1) {
                v0 = bstep(v0, i0, j, k);
                v1 = bstep(v1, i1, j, k);
            }
        keys[i0] = v0; keys[i1] = v1;
        __syncthreads();
        for (int k = 128; k <= 2048; k <<= 1) {
            for (int j = k >> 1; j >= 64; j >>= 1) {
                for (int i = t; i < 2048; i += 1024) {
                    int ixj = i ^ j;
                    if (ixj > i) {
                        u64 a = keys[i], c = keys[ixj];
                        bool desc = ((i & k) == 0);
                        if ((a < c) == desc) { keys[i] = c; keys[ixj] = a; }
                    }
                }
                __syncthreads();
            }
            v0 = keys[i0]; v1 = keys[i1];
            for (int j = 32; j >= 1; j >>= 1) {
                v0 = bstep(v0, i0, j, k);
                v1 = bstep(v1, i1, j, k);
            }
            keys[i0] = v0; keys[i1] = v1;
            __syncthreads();
        }
    }

    // ---- decode top-K into LDS ----
    for (int kk = t; kk < KK; kk += 1024) {
        u64 key = keys[kk];
        float score, cf, box0, box1, box2, box3;
        u32 vld;
        if (kk < (int)cnt2) {
            u32 m = (u32)(key >> 32);
            u32 idx = (u32)MAXIDX - (u32)(key & 0xFFFFFFFFu);
            score = unmapf(m);
            vld = (score > SCORE_THR) ? 1u : 0u;
            int n = idx / CC, c = idx % CC;
            cf = (float)(c + 1);
            const float* r = rois + ((size_t)b * NN + n) * 4;
            const float* d = reg  + ((size_t)b * NN + n) * 4;
            float x1 = r[0], y1 = r[1], x2 = r[2], y2 = r[3];
            float w = x2 - x1, h = y2 - y1;
            float cx = x1 + 0.5f * w, cy = y1 + 0.5f * h;
            float dx = d[0], dy = d[1];
            float dw = fminf(fmaxf(d[2], -MAX_RATIO), MAX_RATIO);
            float dh = fminf(fmaxf(d[3], -MAX_RATIO), MAX_RATIO);
            float pw = w * expf(dw), ph = h * expf(dh);
            float pcx = cx + dx * w, pcy = cy + dy * h;
            box0 = pcx - 0.5f * pw; box1 = pcy - 0.5f * ph;
            box2 = pcx + 0.5f * pw; box3 = pcy + 0.5f * ph;
        } else {
            score = -1.0f; cf = 0.0f; vld = 0u; box0 = box1 = box2 = box3 = 0.0f;
        }
        tb[kk][0] = box0; tb[kk][1] = box1; tb[kk][2] = box2; tb[kk][3] = box3;
        ts[kk] = score; tc[kk] = cf; tv[kk] = vld;
        float off = cf * CLS_OFF;
        ob[kk][0] = box0 + off; ob[kk][1] = box1 + off;
        ob[kk][2] = box2 + off; ob[kk][3] = box3 + off;
    }
    __syncthreads();

    // ---- IoU lower-triangle tiles; mask -> global (plain stores, same-block reader) --
    {
        int wv = t >> 6, lane = t & 63;
        for (int T = wv; T < NTILE; T += 16) {
            int ib = (int)((sqrtf(8.0f * (float)T + 1.0f) - 1.0f) * 0.5f);
            while ((ib + 1) * (ib + 2) / 2 <= T) ++ib;
            while (ib * (ib + 1) / 2 > T) --ib;
            int jbk = T - ib * (ib + 1) / 2;
            int i = ib * 64 + lane;
            if (i < KK) {
                float x1 = ob[i][0], y1 = ob[i][1], x2 = ob[i][2], y2 = ob[i][3];
                float ai = (x2 - x1) * (y2 - y1);
                u64 bits = 0;
                int j0 = jbk * 64;
                int jmax = min(64, KK - j0);
                for (int jj = 0; jj < jmax; ++jj) {
                    float bx1 = ob[j0+jj][0], by1 = ob[j0+jj][1];
                    float bx2 = ob[j0+jj][2], by2 = ob[j0+jj][3];
                    float aj = (bx2 - bx1) * (by2 - by1);
                    float iw = fmaxf(fminf(x2, bx2) - fmaxf(x1, bx1), 0.0f);
                    float ih = fmaxf(fminf(y2, by2) - fmaxf(y1, by1), 0.0f);
                    float inter = iw * ih;
                    float iou = inter / (ai + aj - inter + 1e-9f);
                    if (iou > NMS_THR) bits |= (1ull << jj);
                }
                maskT[((size_t)b * NW + jbk) * KK + i] = bits;
            }
        }
    }
    __syncthreads();   // drains vmcnt: mask writes visible to this block's reads (same L2)

    // ---- ballot fixed-point NMS (first wave), mask via plain loads ----
    if (t < 64) {
        int ln = t;
        const u64* mT = maskT + (size_t)b * NW * KK;
        u64 keptW[NW];
        #pragma unroll
        for (int W = 0; W < NW; ++W) {
            int i = W * 64 + ln;
            bool inr = (i < KK);
            u64 row[NW];
            #pragma unroll
            for (int w = 0; w <= W; ++w)
                row[w] = inr ? mT[(size_t)w * KK + i] : 0ull;
            bool valid = inr && (tv[i] != 0u);
            u64 ext = 0;
            #pragma unroll
            for (int w = 0; w < W; ++w) ext |= keptW[w] & row[w];
            bool cand = valid && (ext == 0ull);
            u64 m_self = row[W] & ((1ull << ln) - 1ull);
            u64 kept = __ballot(cand);
            while (true) {
                u64 k2 = __ballot(cand && ((kept & m_self) == 0ull));
                if (k2 == kept) break;
                kept = k2;
            }
            keptW[W] = kept;
            if (ln == 0) skept[W] = kept;
        }
    }
    __syncthreads();

    // ---- masked output straight from LDS ----
    for (int kk = t; kk < KK; kk += 1024) {
        size_t o = (size_t)b * KK + kk;
        float kf = (float)((skept[kk >> 6] >> (kk & 63)) & 1ull);
        float* op = out + o * 7;
        op[0] = tb[kk][0] * kf; op[1] = tb[kk][1] * kf;
        op[2] = tb[kk][2] * kf; op[3] = tb[kk][3] * kf;
        op[4] = ts[kk] * kf;    op[5] = tc[kk] * kf;    op[6] = kf;
    }
}

extern "C" void kernel_launch(void* const* d_in, const int* in_sizes, int n_in,
                              void* d_out, int out_size, void* d_ws, size_t ws_size,
                              hipStream_t stream) {
    const float* rois   = (const float*)d_in[0];   // (B,N,4)
    const float* scores = (const float*)d_in[1];   // (B*N,C,1,1) == (B, N*C)
    const float* reg    = (const float*)d_in[2];   // (B*N,4,1,1)
    float* out = (float*)d_out;

    char* ws = (char*)d_ws;
    u32* hist1   = (u32*)(ws + WS_HIST1);
    u32* hist2   = (u32*)(ws + WS_HIST2);
    u32* gcount  = (u32*)(ws + WS_GCOUNT);
    u32* gcount2 = (u32*)(ws + WS_GCOUNT2);
    u64* gbuf    = (u64*)(ws + WS_GBUF);
    u64* gbuf2   = (u64*)(ws + WS_GBUF2);
    u64* maskT   = (u64*)(ws + WS_MASK);

    hist1_pass<<<dim3(HB, BB), 1024, 0, stream>>>(scores, hist1, hist2, gcount);

    stage_pass<<<dim3(SGB, BB), 256, 0, stream>>>(scores, hist1, hist2, gbuf, gcount);

    refine_pass<<<dim3(D4X, BB), 1024, 0, stream>>>(
        gbuf, gcount, hist1, hist2, gbuf2, gcount2);

    tail_pass<<<BB, 1024, 0, stream>>>(gbuf2, gcount2, rois, reg, maskT, out);
}

// Round 15
// 91.887 us; speedup vs baseline: 2.2434x; 2.2434x over previous
//
#include <hip/hip_runtime.h>
#include <stdint.h>

typedef unsigned int u32;
typedef unsigned long long u64;

#define BB 8
#define NN 8192
#define CC 80
#define KK 1000
#define NC (NN*CC)            // 655360
#define MAXIDX (NC-1)
#define NMS_THR 0.5f
#define SCORE_THR 0.05f
#define MAX_RATIO 4.135166556742356f
#define CLS_OFF 10000.0f
#define CAP 2048
#define NW 16                 // u64 words per mask row
#define HB 8                  // hist1 sub-blocks per batch (1024 thr each)
#define SGB 128               // stage blocks per batch
#define D4X 8                 // refine/rank blocks per batch (1024 thr each)
#define D5X 34                // iou/nms blocks per batch (34*4 = 136 tiles)
#define LBUF 1024             // stage per-block staging buffer (u64)
#define GBUFCAP 98304         // per-batch superset capacity (u64)

#define SC_AGENT __HIP_MEMORY_SCOPE_AGENT

// ---- workspace layout (bytes) ----
#define WS_HIST1   0          // BB*HB*2048*4 = 524288 (private slices, plain stores)
#define WS_HIST2   524288     // BB*2048*4 = 65536 (atomic-accumulated; zeroed by hist1)
#define WS_CTRL    589824     // 32 u32: gcount(8), tick5(8), gcount2(8), spare(8)
#define WS_GCOUNT  589824
#define WS_TICK5   589856
#define WS_GCOUNT2 589888
#define WS_GBUF    589952     // 8*98304*8 = 6291456 -> 6881408
#define WS_GBUF2   6881408    // 8*2048*8 = 131072 -> 7012480
#define WS_TBOX    7012480    // 128000
#define WS_TOBOX   7140480    // 128000
#define WS_TSCORE  7268480    // 32000
#define WS_TCLS    7300480    // 32000
#define WS_TVALID  7332480    // 32000
#define WS_MASK    7364480    // 8*16*1000*8 = 1024000 -> 8388480

__device__ __forceinline__ u32 mapf(float f) {
    u32 u = __float_as_uint(f);
    return (u & 0x80000000u) ? ~u : (u | 0x80000000u);
}
__device__ __forceinline__ float unmapf(u32 m) {
    u32 u = (m & 0x80000000u) ? (m ^ 0x80000000u) : ~m;
    return __uint_as_float(u);
}

// ---------------- D1: private 11-bit histograms + fold-in zeroing of control bufs -----
__global__ __launch_bounds__(1024) void hist1_pass(const float* __restrict__ scores,
                                                   u32* __restrict__ hist1,
                                                   u32* __restrict__ hist2,
                                                   u32* __restrict__ ctrl /* 32 u32 */) {
    __shared__ u32 lh[2048];
    int b = blockIdx.y, blk = blockIdx.x, t = threadIdx.x;
    for (int i = t; i < 2048; i += 1024) lh[i] = 0;
    // zero hist2 slice (each of the 64 blocks zeroes 256 u32) and ctrl (block 0,0)
    if (t < 256) hist2[(b * HB + blk) * 256 + t] = 0u;
    else if (t < 288 && b == 0 && blk == 0) ctrl[t - 256] = 0u;
    __syncthreads();
    const float4* sp = (const float4*)(scores + (size_t)b * NC);
    int nvec = NC / 4;
    for (int v = blk * 1024 + t; v < nvec; v += HB * 1024) {
        float4 s4 = sp[v];
        float ss[4] = {s4.x, s4.y, s4.z, s4.w};
        #pragma unroll
        for (int q = 0; q < 4; ++q) {
            float s = ss[q] > SCORE_THR ? ss[q] : -1.0f;
            atomicAdd(&lh[mapf(s) >> 21], 1u);
        }
    }
    __syncthreads();
    u32* ho = hist1 + ((size_t)b * HB + blk) * 2048;
    for (int i = t; i < 2048; i += 1024) ho[i] = lh[i];
}

// ---- fast digit selects: wave shfl suffix-scan, 2 barriers total ----
// 256-thread version, 8 bins/thread (descending). bc[0]=digit, bc[1]=rem.
__device__ __forceinline__ void sel8_fast(const u32 hv[8], u32 need,
                                          u32* wt, u32* wsuf, u32* bc) {
    int t = threadIdx.x, l = t & 63, w = t >> 6;   // 4 waves
    u32 s = 0;
    #pragma unroll
    for (int q = 0; q < 8; ++q) s += hv[q];
    u32 x = s;
    #pragma unroll
    for (int off = 1; off < 64; off <<= 1) {
        u32 y = __shfl_down(x, off);
        if (l + off < 64) x += y;
    }
    if (l == 0) wt[w] = x;
    __syncthreads();
    if (w == 0) {
        u32 v = (l < 4) ? wt[l] : 0u;
        #pragma unroll
        for (int off = 1; off < 4; off <<= 1) {
            u32 y = __shfl_down(v, off);
            if (l + off < 4) v += y;
        }
        if (l < 4) wsuf[l] = v;
    }
    __syncthreads();
    u32 sufAll = x + ((w < 3) ? wsuf[w + 1] : 0u);
    u32 cumAbove = sufAll - s;
    if (cumAbove < need && sufAll >= need) {
        u32 cum = cumAbove;
        int d = t * 8;
        #pragma unroll
        for (int q = 7; q >= 0; --q) {
            if (cum + hv[q] >= need) { d = t * 8 + q; break; }
            cum += hv[q];
        }
        bc[0] = (u32)d;
        bc[1] = need - cum;
    }
    __syncthreads();
}

// 1024-thread version, 2 bins/thread (descending). bc[0]=digit, bc[1]=rem.
__device__ __forceinline__ void sel2_fast(u32 hv0, u32 hv1, u32 need,
                                          u32* wt, u32* wsuf, u32* bc) {
    int t = threadIdx.x, l = t & 63, w = t >> 6;   // 16 waves
    u32 s = hv0 + hv1;
    u32 x = s;
    #pragma unroll
    for (int off = 1; off < 64; off <<= 1) {
        u32 y = __shfl_down(x, off);
        if (l + off < 64) x += y;
    }
    if (l == 0) wt[w] = x;
    __syncthreads();
    if (w == 0) {
        u32 v = (l < 16) ? wt[l] : 0u;
        #pragma unroll
        for (int off = 1; off < 16; off <<= 1) {
            u32 y = __shfl_down(v, off);
            if (l + off < 16) v += y;
        }
        if (l < 16) wsuf[l] = v;
    }
    __syncthreads();
    u32 sufAll = x + ((w < 15) ? wsuf[w + 1] : 0u);
    u32 cumAbove = sufAll - s;
    if (cumAbove < need && sufAll >= need) {
        if (cumAbove + hv1 >= need) { bc[0] = 2u * t + 1u; bc[1] = need - cumAbove; }
        else                        { bc[0] = 2u * t;      bc[1] = need - cumAbove - hv1; }
    }
    __syncthreads();
}

// ---------------- D2: stage d0-superset + build hist2 (bits 20..10 of d0-items) ------
__global__ __launch_bounds__(256) void stage_pass(
    const float* __restrict__ scores, const u32* __restrict__ hist1,
    u32* __restrict__ hist2, u64* __restrict__ gbuf, u32* __restrict__ gcount) {
    __shared__ u64 buf[LBUF];
    __shared__ u32 h2[2048];
    __shared__ u32 wt[4], wsuf[4];
    __shared__ u32 bc[2];
    __shared__ u32 lcnt, lbase;
    int b = blockIdx.y, bx = blockIdx.x, t = threadIdx.x;
    for (int i = t; i < 2048; i += 256) h2[i] = 0;
    if (t == 0) lcnt = 0;
    u32 hv[8];
    {
        const u32* h = hist1 + (size_t)b * HB * 2048;
        #pragma unroll
        for (int q = 0; q < 8; ++q) {
            u32 v = 0;
            #pragma unroll
            for (int sb = 0; sb < HB; ++sb) v += h[sb * 2048 + t * 8 + q];
            hv[q] = v;
        }
    }
    __syncthreads();
    sel8_fast(hv, (u32)KK, wt, wsuf, bc);
    u32 d0 = bc[0];
    const float4* sp = (const float4*)(scores + (size_t)b * NC);
    int nvec = NC / 4;
    for (int v = bx * 256 + t; v < nvec; v += SGB * 256) {
        float4 s4 = sp[v];
        float ss[4] = {s4.x, s4.y, s4.z, s4.w};
        #pragma unroll
        for (int q = 0; q < 4; ++q) {
            float s = ss[q] > SCORE_THR ? ss[q] : -1.0f;
            u32 m = mapf(s);
            u32 top = m >> 21;
            if (top >= d0) {
                u32 p = atomicAdd(&lcnt, 1u);
                if (p < LBUF) {
                    u32 idx = (u32)(v * 4 + q);
                    buf[p] = ((u64)m << 32) | (u64)(MAXIDX - idx);
                }
                if (top == d0) atomicAdd(&h2[(m >> 10) & 0x7FFu], 1u);
            }
        }
    }
    __syncthreads();
    for (int i = t; i < 2048; i += 256)
        if (h2[i]) atomicAdd(&hist2[b * 2048 + i], h2[i]);
    if (t == 0) {
        u32 c = lcnt; if (c > LBUF) c = LBUF;
        lcnt = c;
        lbase = atomicAdd(&gcount[b], c);
    }
    __syncthreads();
    u32 c = lcnt, base = lbase;
    for (u32 i = t; i < c; i += 256) {
        u32 p = base + i;
        if (p < GBUFCAP) gbuf[(size_t)b * GBUFCAP + p] = buf[i];
    }
}

// ---------------- D3: exact 22-bit filter of staged superset -> gbuf2 ----------------
__global__ __launch_bounds__(1024) void refine_pass(
    const u64* __restrict__ gbuf, const u32* __restrict__ gcount,
    const u32* __restrict__ hist1, const u32* __restrict__ hist2,
    u64* __restrict__ gbuf2, u32* __restrict__ gcount2) {
    __shared__ u64 keys[CAP];
    __shared__ u32 wt[16], wsuf[16];
    __shared__ u32 bc[2];
    __shared__ u32 lcnt, lbase;
    int b = blockIdx.y, bx = blockIdx.x, t = threadIdx.x;
    if (t == 0) lcnt = 0;
    u32 hv0 = 0, hv1 = 0;
    {
        const u32* h = hist1 + (size_t)b * HB * 2048;
        #pragma unroll
        for (int sb = 0; sb < HB; ++sb) {
            hv0 += h[sb * 2048 + 2 * t];
            hv1 += h[sb * 2048 + 2 * t + 1];
        }
    }
    __syncthreads();
    sel2_fast(hv0, hv1, (u32)KK, wt, wsuf, bc);
    u32 d0 = bc[0], rem = bc[1];
    __syncthreads();
    sel2_fast(hist2[b * 2048 + 2 * t], hist2[b * 2048 + 2 * t + 1], rem, wt, wsuf, bc);
    u32 thr = ((d0 << 11) | bc[0]) << 10;

    u32 cnt = gcount[b]; if (cnt > GBUFCAP) cnt = GBUFCAP;
    const u64* gb = gbuf + (size_t)b * GBUFCAP;
    u32 chunk = (cnt + D4X - 1) / D4X;
    u32 lo = bx * chunk, hi = lo + chunk; if (hi > cnt) hi = cnt;
    for (u32 i = lo + t; i < hi; i += 1024) {
        u64 key = gb[i];
        if ((u32)(key >> 32) >= thr) {
            u32 p = atomicAdd(&lcnt, 1u);
            if (p < CAP) keys[p] = key;
        }
    }
    __syncthreads();
    if (t == 0) {
        u32 c = lcnt; if (c > CAP) c = CAP;
        lcnt = c;
        lbase = atomicAdd(&gcount2[b], c);      // default atomicAdd = device scope
    }
    __syncthreads();
    u32 c = lcnt, base = lbase;
    for (u32 i = t; i < c; i += 1024) {
        u32 p = base + i;
        if (p < CAP) gbuf2[(size_t)b * CAP + p] = keys[i];   // plain stores
    }
}

// decode one candidate key at output row r
__device__ __forceinline__ void decode_row(
    int b, u32 r, u64 key,
    const float* __restrict__ rois, const float* __restrict__ reg,
    float* __restrict__ tbox, float* __restrict__ tobox,
    float* __restrict__ tscore, float* __restrict__ tcls, u32* __restrict__ tvalid) {
    u32 m = (u32)(key >> 32);
    u32 idx = (u32)MAXIDX - (u32)(key & 0xFFFFFFFFu);
    float score = unmapf(m);
    u32 vld = (score > SCORE_THR) ? 1u : 0u;
    int n = idx / CC, c = idx % CC;
    float cf = (float)(c + 1);
    const float* rr = rois + ((size_t)b * NN + n) * 4;
    const float* d  = reg  + ((size_t)b * NN + n) * 4;
    float x1 = rr[0], y1 = rr[1], x2 = rr[2], y2 = rr[3];
    float w = x2 - x1, h = y2 - y1;
    float cx = x1 + 0.5f * w, cy = y1 + 0.5f * h;
    float dx = d[0], dy = d[1];
    float dw = fminf(fmaxf(d[2], -MAX_RATIO), MAX_RATIO);
    float dh = fminf(fmaxf(d[3], -MAX_RATIO), MAX_RATIO);
    float pw = w * expf(dw), ph = h * expf(dh);
    float pcx = cx + dx * w, pcy = cy + dy * h;
    float box0 = pcx - 0.5f * pw, box1 = pcy - 0.5f * ph;
    float box2 = pcx + 0.5f * pw, box3 = pcy + 0.5f * ph;
    size_t o = (size_t)b * KK + r;
    tscore[o] = score; tcls[o] = cf; tvalid[o] = vld;
    float off = cf * CLS_OFF;
    tbox[o*4+0] = box0; tbox[o*4+1] = box1; tbox[o*4+2] = box2; tbox[o*4+3] = box3;
    tobox[o*4+0] = box0 + off; tobox[o*4+1] = box1 + off;
    tobox[o*4+2] = box2 + off; tobox[o*4+3] = box3 + off;
}

// ---------------- D4: rank-by-counting over refined set + decode (wide, no sort) -----
__global__ __launch_bounds__(1024) void rank_decode(
    const u64* __restrict__ gbuf2, const u32* __restrict__ gcount2,
    const float* __restrict__ rois, const float* __restrict__ reg,
    float* __restrict__ tbox, float* __restrict__ tobox,
    float* __restrict__ tscore, float* __restrict__ tcls, u32* __restrict__ tvalid) {
    __shared__ u64 kk_[CAP];       // all candidate keys (16 KB)
    __shared__ u32 rnk[(CAP + D4X - 1) / D4X];   // ranks for this block's chunk
    int b = blockIdx.y, bx = blockIdx.x, t = threadIdx.x;
    int wv = t >> 6, ln = t & 63;  // 16 waves
    u32 cnt2 = gcount2[b]; if (cnt2 > CAP) cnt2 = CAP;
    for (int i = t; i < (int)cnt2; i += 1024)
        kk_[i] = gbuf2[(size_t)b * CAP + i];
    __syncthreads();
    u32 chunk = (cnt2 + D4X - 1) / D4X;
    u32 lo = bx * chunk, hi = lo + chunk; if (hi > cnt2) hi = cnt2;
    // wave-per-candidate: 64 lanes split the cnt2 keys, shuffle-reduce the count
    for (u32 ci = lo + wv; ci < hi; ci += 16) {
        u64 my = kk_[ci];
        u32 cgt = 0;
        for (u32 j = ln; j < cnt2; j += 64)
            cgt += (kk_[j] > my) ? 1u : 0u;
        #pragma unroll
        for (int off = 32; off >= 1; off >>= 1)
            cgt += __shfl_down(cgt, off);
        if (ln == 0) rnk[ci - lo] = cgt;
    }
    __syncthreads();
    // decode this block's chunk at row=rank (ranks unique -> no conflicts)
    for (u32 i = lo + t; i < hi; i += 1024) {
        u32 r = rnk[i - lo];
        if (r < KK) decode_row(b, r, kk_[i], rois, reg,
                               tbox, tobox, tscore, tcls, tvalid);
    }
    // filler rows [cnt2, KK)
    if (bx == 0) {
        for (u32 r = cnt2 + t; r < KK; r += 1024) {
            size_t o = (size_t)b * KK + r;
            tscore[o] = -1.0f; tcls[o] = 0.0f; tvalid[o] = 0u;
            tbox[o*4+0] = 0.0f; tbox[o*4+1] = 0.0f; tbox[o*4+2] = 0.0f; tbox[o*4+3] = 0.0f;
            tobox[o*4+0] = 0.0f; tobox[o*4+1] = 0.0f; tobox[o*4+2] = 0.0f; tobox[o*4+3] = 0.0f;
        }
    }
}

// ---------------- D5: IoU tiles (lower triangle) -> ticket-last block does NMS -------
__global__ __launch_bounds__(256) void iou_nms(
    const float* __restrict__ tobox, const u32* __restrict__ tvalid,
    const float* __restrict__ tbox, const float* __restrict__ tscore,
    const float* __restrict__ tcls,
    u64* __restrict__ maskT, u32* __restrict__ tick, float* __restrict__ out) {
    __shared__ float jbs[4][64][4];
    __shared__ u64 skept[NW];
    __shared__ int islast;
    int b = blockIdx.y, bx = blockIdx.x, t = threadIdx.x;
    int g = t >> 6, lane = t & 63;
    int T = bx * 4 + g;                      // 0..135 (34*4 = 136)
    {
        int ib = (int)((sqrtf(8.0f * (float)T + 1.0f) - 1.0f) * 0.5f);
        while ((ib + 1) * (ib + 2) / 2 <= T) ++ib;
        while (ib * (ib + 1) / 2 > T) --ib;
        int jbk = T - ib * (ib + 1) / 2;
        int j0 = jbk * 64;
        int jg = j0 + lane;
        float* jb = jbs[g][lane];
        if (jg < KK) {
            const float* p = tobox + ((size_t)b * KK + jg) * 4;
            jb[0] = p[0]; jb[1] = p[1]; jb[2] = p[2]; jb[3] = p[3];
        } else {
            jb[0] = 0; jb[1] = 0; jb[2] = 0; jb[3] = 0;
        }
        // jbs[g] written/read only by this 64-lane wave -> no barrier needed
        int i = ib * 64 + lane;
        if (i < KK) {
            const float* p = tobox + ((size_t)b * KK + i) * 4;
            float x1 = p[0], y1 = p[1], x2 = p[2], y2 = p[3];
            float ai = (x2 - x1) * (y2 - y1);
            u64 bits = 0;
            int jmax = min(64, KK - j0);
            for (int jj = 0; jj < jmax; ++jj) {
                const float* q = jbs[g][jj];
                float bx1 = q[0], by1 = q[1], bx2 = q[2], by2 = q[3];
                float aj = (bx2 - bx1) * (by2 - by1);
                float iw = fmaxf(fminf(x2, bx2) - fmaxf(x1, bx1), 0.0f);
                float ih = fmaxf(fminf(y2, by2) - fmaxf(y1, by1), 0.0f);
                float inter = iw * ih;
                float iou = inter / (ai + aj - inter + 1e-9f);
                if (iou > NMS_THR) bits |= (1ull << jj);
            }
            __hip_atomic_store(&maskT[((size_t)b * NW + jbk) * KK + i], bits,
                               __ATOMIC_RELAXED, SC_AGENT);
        }
    }
    __syncthreads();
    if (t == 0) {
        u32 tk = __hip_atomic_fetch_add(&tick[b], 1u, __ATOMIC_ACQ_REL, SC_AGENT);
        islast = (tk == (u32)(D5X - 1)) ? 1 : 0;
    }
    __syncthreads();
    if (!islast) return;

    // ---- last block: ballot fixed-point NMS from device-coherent mask ----
    if (t < 64) {
        int ln = t;
        const u64* mT = maskT + (size_t)b * NW * KK;
        u64 keptW[NW];
        #pragma unroll
        for (int W = 0; W < NW; ++W) {
            int i = W * 64 + ln;
            bool inr = (i < KK);
            u64 row[NW];
            #pragma unroll
            for (int w = 0; w <= W; ++w)
                row[w] = inr ? __hip_atomic_load(&mT[(size_t)w * KK + i],
                                                 __ATOMIC_RELAXED, SC_AGENT) : 0ull;
            bool valid = inr && (tvalid[(size_t)b * KK + i] != 0u);
            u64 ext = 0;
            #pragma unroll
            for (int w = 0; w < W; ++w) ext |= keptW[w] & row[w];
            bool cand = valid && (ext == 0ull);
            u64 m_self = row[W] & ((1ull << ln) - 1ull);
            u64 kept = __ballot(cand);
            while (true) {
                u64 k2 = __ballot(cand && ((kept & m_self) == 0ull));
                if (k2 == kept) break;
                kept = k2;
            }
            keptW[W] = kept;
            if (ln == 0) skept[W] = kept;
        }
    }
    __syncthreads();
    for (int kk = t; kk < KK; kk += 256) {
        size_t o = (size_t)b * KK + kk;
        float kf = (float)((skept[kk >> 6] >> (kk & 63)) & 1ull);
        float* op = out + o * 7;
        op[0] = tbox[o*4+0] * kf; op[1] = tbox[o*4+1] * kf;
        op[2] = tbox[o*4+2] * kf; op[3] = tbox[o*4+3] * kf;
        op[4] = tscore[o] * kf;   op[5] = tcls[o] * kf;   op[6] = kf;
    }
}

extern "C" void kernel_launch(void* const* d_in, const int* in_sizes, int n_in,
                              void* d_out, int out_size, void* d_ws, size_t ws_size,
                              hipStream_t stream) {
    const float* rois   = (const float*)d_in[0];   // (B,N,4)
    const float* scores = (const float*)d_in[1];   // (B*N,C,1,1) == (B, N*C)
    const float* reg    = (const float*)d_in[2];   // (B*N,4,1,1)
    float* out = (float*)d_out;

    char* ws = (char*)d_ws;
    u32* hist1   = (u32*)(ws + WS_HIST1);
    u32* hist2   = (u32*)(ws + WS_HIST2);
    u32* gcount  = (u32*)(ws + WS_GCOUNT);
    u32* tick5   = (u32*)(ws + WS_TICK5);
    u32* gcount2 = (u32*)(ws + WS_GCOUNT2);
    u64* gbuf    = (u64*)(ws + WS_GBUF);
    u64* gbuf2   = (u64*)(ws + WS_GBUF2);
    float* tbox   = (float*)(ws + WS_TBOX);
    float* tobox  = (float*)(ws + WS_TOBOX);
    float* tscore = (float*)(ws + WS_TSCORE);
    float* tcls   = (float*)(ws + WS_TCLS);
    u32*   tvalid = (u32*)(ws + WS_TVALID);
    u64*   maskT  = (u64*)(ws + WS_MASK);

    hist1_pass<<<dim3(HB, BB), 1024, 0, stream>>>(scores, hist1, hist2, gcount);

    stage_pass<<<dim3(SGB, BB), 256, 0, stream>>>(scores, hist1, hist2, gbuf, gcount);

    refine_pass<<<dim3(D4X, BB), 1024, 0, stream>>>(
        gbuf, gcount, hist1, hist2, gbuf2, gcount2);

    rank_decode<<<dim3(D4X, BB), 1024, 0, stream>>>(
        gbuf2, gcount2, rois, reg, tbox, tobox, tscore, tcls, tvalid);

    iou_nms<<<dim3(D5X, BB), 256, 0, stream>>>(
        tobox, tvalid, tbox, tscore, tcls, maskT, tick5, out);
}